// Round 6
// baseline (764.587 us; speedup 1.0000x reference)
//
#include <hip/hip_runtime.h>
#include <cstdint>
#include <cstddef>

// ============================================================================
// transformer_11441792877290 — MI355X fp32, round 12
// B=4 S=1024 E=1024 H=16 DK=64 FF=2048, SCALE=8, EPS=1e-5
// vs round 11 (747us; reg-dbuf rotation undone by compiler regalloc — VGPR
// stayed 88, schedule reverted to serial) and round 10 (690.7us, best):
//  * gemm_k restored to the r10 body exactly (Wo1/Q2/Wo2/FFN2).
//  * NEW gemm2_k for QKV1/KV2/FFN1: 256 thr (4 waves, 2x2), tile 128x128,
//    ring-2 LDS (64KB -> 2 blocks/CU; each SIMD hosts one wave of EACH
//    block -> independent barriers anti-phase the read-storm of one block
//    against the MFMA phase of the other; the LDS/MFMA overlap that r7/r11
//    could not get from intra-block scheduling comes from TLP).
//    Loop: vmcnt(0)+barrier; stage(kt+1 -> other slot); ds_read; MFMA.
//    Safety: each wave's vmcnt(0) precedes its barrier -> post-barrier all
//    waves' gload_lds landed; restage target slot's reads retired pre-
//    barrier (MFMA data dependence). T2 swizzle kept (0 conflicts).
//  Per-element term order hh->hl->lh preserved -> bit-identical results.
// ============================================================================

#define DI __device__ __forceinline__
#define MFMA __builtin_amdgcn_mfma_f32_16x16x32_bf16

typedef short s8v __attribute__((ext_vector_type(8)));
typedef float f4v __attribute__((ext_vector_type(4)));
typedef unsigned u4v __attribute__((ext_vector_type(4)));

DI float bf2f(short u){
  union { unsigned int i; float f; } v;
  v.i = ((unsigned int)(unsigned short)u) << 16;
  return v.f;
}
DI short f2bf(float f){  // round-to-nearest-even
  union { float f; unsigned int i; } v; v.f = f;
  unsigned int x = v.i;
  return (short)((x + 0x7fffu + ((x >> 16) & 1u)) >> 16);
}
DI unsigned pack2(short hi, short lo){
  return ((unsigned)(unsigned short)lo << 16) | (unsigned)(unsigned short)hi;
}
DI unsigned packf(float val){
  short hi = f2bf(val);
  return pack2(hi, f2bf(val - bf2f(hi)));
}
DI void gload16(const void* g, void* l){
  __builtin_amdgcn_global_load_lds(
      (const __attribute__((address_space(1))) unsigned*)g,
      (__attribute__((address_space(3))) unsigned*)l, 16, 0, 0);
}

// ---------------------------------------------------------------------------
// fp32 -> bf16 hi/lo plane split (OE, IR)
// ---------------------------------------------------------------------------
struct SplitP { const float* src[2]; short* hi[2]; short* lo[2]; };

__launch_bounds__(256)
__global__ void splitall_k(SplitP sp){
  const int t = blockIdx.y;
  int i = (blockIdx.x * 256 + threadIdx.x) << 2;
  float4 v = *(const float4*)(sp.src[t] + i);
  float xs[4] = {v.x, v.y, v.z, v.w};
  short h[4], l[4];
  #pragma unroll
  for (int c = 0; c < 4; c++){
    h[c] = f2bf(xs[c]);
    l[c] = f2bf(xs[c] - bf2f(h[c]));
  }
  *(short4*)(sp.hi[t] + i) = make_short4(h[0], h[1], h[2], h[3]);
  *(short4*)(sp.lo[t] + i) = make_short4(l[0], l[1], l[2], l[3]);
}

// ---------------------------------------------------------------------------
// Batched weight transpose: fp32 [K][N] (or [H][E][DK] qkv gather) ->
// bf16 hi/lo planes [N][K]. 64x64 tiles via LDS.
// ---------------------------------------------------------------------------
struct TransP {
  const float* src[10];
  short* oh[10]; short* ol[10];
  int Kd[10]; int Nd[10]; int qkv[10]; int ntiles[10];
};

__launch_bounds__(256)
__global__ void transall_k(TransP tp){
  const int t = blockIdx.y;
  const int tile = blockIdx.x;
  if (tile >= tp.ntiles[t]) return;
  const int K = tp.Kd[t], N = tp.Nd[t];
  const int ncols = N >> 6;
  const int n0 = (tile % ncols) << 6, k0 = (tile / ncols) << 6;
  __shared__ float Ld[64 * 65];
  const int tid = threadIdx.x;
  const int row = tid >> 2, c16 = (tid & 3) << 4;
  const float* s = tp.src[t];
  size_t base;
  if (tp.qkv[t]) base = ((size_t)(n0 >> 6) << 16) + ((size_t)(k0 + row) << 6) + c16;
  else           base = (size_t)(k0 + row) * N + n0 + c16;
  #pragma unroll
  for (int j4 = 0; j4 < 4; j4++){
    float4 v = *(const float4*)(s + base + (j4 << 2));
    int c = row * 65 + c16 + (j4 << 2);
    Ld[c] = v.x; Ld[c + 1] = v.y; Ld[c + 2] = v.z; Ld[c + 3] = v.w;
  }
  __syncthreads();
  const int n = tid >> 2;
  s8v h0, h1, l0, l1;
  #pragma unroll
  for (int j = 0; j < 8; j++){
    float a = Ld[(c16 + j) * 65 + n];
    float b = Ld[(c16 + 8 + j) * 65 + n];
    short ha = f2bf(a), hb = f2bf(b);
    h0[j] = ha; l0[j] = f2bf(a - bf2f(ha));
    h1[j] = hb; l1[j] = f2bf(b - bf2f(hb));
  }
  size_t ob = (size_t)(n0 + n) * K + k0 + c16;
  *(s8v*)(tp.oh[t] + ob)     = h0;
  *(s8v*)(tp.oh[t] + ob + 8) = h1;
  *(s8v*)(tp.ol[t] + ob)     = l0;
  *(s8v*)(tp.ol[t] + ob + 8) = l1;
}

// ---------------------------------------------------------------------------
// Shared GEMM param block.
// EPI 0: packed q scatter              2: fp32 = acc + xres
//     3: hi/lo planes = relu(acc+bias) 4: fp32 = acc + bias
//     6: QKV packed (q / K2^T / V^T)   7: KV packed (K2^T / V^T)
// ---------------------------------------------------------------------------
struct GemmP {
  const short* Ah; const short* Al; int lda;
  const short* Bh; const short* Bl; int ldb;
  int K; int N;
  const float* xres; const float* bias;
  float* outf;
  short* o1h; short* o1l;
  unsigned* p1; unsigned* p2; unsigned* p3;
};

// epilogue shared by both GEMM kernels
template<int EPI, int NB>
DI void gemm_epilogue(const GemmP& p, f4v (&acc)[4][NB],
                      int m0, int n0, int mo, int no, int lr, int lg){
  #pragma unroll
  for (int mi = 0; mi < 4; mi++){
    #pragma unroll
    for (int ni = 0; ni < NB; ni++){
      #pragma unroll
      for (int r = 0; r < 4; r++){
        float val = acc[mi][ni][r];
        int m = m0 + mo + (mi << 4) + (lg << 2) + r;
        int n = n0 + no + (ni << 4) + lr;
        if (EPI == 2){
          size_t o = (size_t)m * p.N + n;
          p.outf[o] = val + p.xres[o];
        } else if (EPI == 4){
          p.outf[(size_t)m * p.N + n] = val + p.bias[n];
        } else if (EPI == 3){
          float x = val + p.bias[n];
          x = x > 0.0f ? x : 0.0f;
          size_t o = (size_t)m * p.N + n;
          short hi = f2bf(x);
          p.o1h[o] = hi;
          p.o1l[o] = f2bf(x - bf2f(hi));
        } else {
          // packed scatter: EPI 0 (q), 6 (q/K2^T/V^T), 7 (K2^T/V^T)
          int seg = (EPI == 0) ? 0 : (n >> 10);
          int n1 = (EPI == 0) ? n : (n & 1023);
          int kind = (EPI == 0) ? 0 : (EPI == 6 ? seg : seg + 1);
          int b = m >> 10, s = m & 1023, hh = n1 >> 6, d = n1 & 63;
          size_t hb16 = (size_t)((hh << 2) | b) << 16;
          size_t dst;
          if (kind == 0)      dst = hb16 + ((size_t)s << 6) + d;
          else if (kind == 1) dst = hb16 + ((size_t)(((s & 15) << 6) | d) << 6) + (s >> 4);
          else                dst = hb16 + ((size_t)d << 10) + s;
          unsigned* dp = (EPI == 0) ? p.p1
                       : (EPI == 6) ? (seg == 0 ? p.p1 : (seg == 1 ? p.p2 : p.p3))
                                    : (seg == 0 ? p.p1 : p.p2);
          dp[dst] = packf(val);
        }
      }
    }
  }
}

// ---------------------------------------------------------------------------
// gemm_k (r10 structure, unchanged): 512 thr = 8 waves; tile TM x 128,
// BK=32; ring-3 LDS, distance-2 prefetch, vmcnt(NG)+barrier per kt,
// single compiler-scheduled region, 1 block/CU. T2 swizzle.
// ---------------------------------------------------------------------------
template<int TM, int EPI, int TERMS>
__launch_bounds__(512, 2)
__global__ void gemm_k(GemmP p){
  constexpr int AGR = TM * 4;                    // Ah granules (16B) per tile
  constexpr int NGRAN = (TERMS == 3 ? 2 * AGR : AGR) + 1024;  // + Bh + Bl
  constexpr int NG = NGRAN >> 9;                 // gll per wave per tile
  constexpr int WM = TM >> 6;                    // waves along m (4 or 2)
  constexpr int NB = 128 / (8 / WM) / 16;        // n-frags per wave (4 or 2)
  __shared__ short AhL[3][TM * 32];
  __shared__ short AlL[3][(TERMS == 3) ? TM * 32 : 8];
  __shared__ short BhL[3][128 * 32];
  __shared__ short BlL[3][128 * 32];
  const int tid = threadIdx.x;
  const int L = tid & 63, w = tid >> 6;
  const int lr = L & 15, lg = L >> 4;
  const int mo = (w & (WM - 1)) << 6;
  const int no = (w / WM) * (NB << 4);

  // ---- XCD swizzle: flat%8 = xcd; within xcd, n varies fastest
  const int gx = gridDim.x, gy = gridDim.y;
  const int f = blockIdx.y * gx + blockIdx.x;
  const int j = f >> 3;
  const int jm = j / gx;
  const int mb = (f & 7) * (gy >> 3) + jm;
  const int nb = j - jm * gx;
  const int m0 = mb * TM, n0 = nb << 7;

  const int lrow4 = L >> 2, lq = L & 3;

  // ---- swizzled LDS read offsets; row r's k-granule g lives at LDS granule
  // g ^ ((r>>1)&3) -> conflict-free (rocprof-verified 0)
  int aoff[4], boff[NB];
  #pragma unroll
  for (int mi = 0; mi < 4; mi++){
    int r = mo + (mi << 4) + lr;
    aoff[mi] = (r << 5) + ((lg ^ ((r >> 1) & 3)) << 3);
  }
  #pragma unroll
  for (int ni = 0; ni < NB; ni++){
    int n = no + (ni << 4) + lr;
    boff[ni] = (n << 5) + ((lg ^ ((n >> 1) & 3)) << 3);
  }

  f4v acc[4][NB];
  #pragma unroll
  for (int i = 0; i < 4; i++)
    #pragma unroll
    for (int jj = 0; jj < NB; jj++)
      #pragma unroll
      for (int r = 0; r < 4; r++) acc[i][jj][r] = 0.0f;

  const int nkt = p.K >> 5;

  // stage tile into ring slot; source col granule pre-swizzled so the
  // linear gload_lds destination lands swizzled
  auto stage = [&](int tile, int slot){
    const int k0 = tile << 5;
    #pragma unroll
    for (int i = 0; i < NG; i++){
      int base_c = (i << 9) + (w << 6);    // wave-uniform granule index
      const short* plane; short* lds; int row0; int ld; int pc;
      if (base_c < AGR){
        pc = base_c; plane = p.Ah; lds = &AhL[slot][0]; row0 = m0; ld = p.lda;
      } else if (TERMS == 3 && base_c < 2 * AGR){
        pc = base_c - AGR; plane = p.Al; lds = &AlL[slot][0]; row0 = m0; ld = p.lda;
      } else {
        int pc2 = base_c - (TERMS == 3 ? 2 * AGR : AGR);
        if (pc2 < 512){ pc = pc2; plane = p.Bh; lds = &BhL[slot][0]; }
        else          { pc = pc2 - 512; plane = p.Bl; lds = &BlL[slot][0]; }
        row0 = n0; ld = p.ldb;
      }
      int rl = (pc >> 2) + lrow4;                 // row within tile
      int sc = (lq ^ ((rl >> 1) & 3)) << 3;       // swizzled source granule
      gload16(plane + (size_t)(row0 + rl) * ld + k0 + sc, lds + (pc << 3));
    }
  };

  // prologue: tiles 0,1 -> slots 0,1
  stage(0, 0);
  stage(1, 1);

  for (int kt = 0; kt < nkt; kt++){
    const int cur = kt % 3;
    // wait until only the kt+1 prefetch (NG gll) remains in flight, then sync
    asm volatile("s_waitcnt vmcnt(%0)\n\ts_barrier" :: "i"(NG) : "memory");

    s8v a_h[4], a_l[4], b_h[NB], b_l[NB];
    #pragma unroll
    for (int mi = 0; mi < 4; mi++){
      a_h[mi] = *(const s8v*)&AhL[cur][aoff[mi]];
      if (TERMS == 3) a_l[mi] = *(const s8v*)&AlL[cur][aoff[mi]];
    }
    #pragma unroll
    for (int ni = 0; ni < NB; ni++){
      b_h[ni] = *(const s8v*)&BhL[cur][boff[ni]];
      b_l[ni] = *(const s8v*)&BlL[cur][boff[ni]];
    }

    // issue distance-2 prefetch (clamped at the end to keep vmcnt cadence;
    // re-staging the last tile into a dead slot is idempotent/harmless)
    int nt = kt + 2 < nkt ? kt + 2 : nkt - 1;
    stage(nt, (kt + 2) % 3);

    #pragma unroll
    for (int ni = 0; ni < NB; ni++){
      #pragma unroll
      for (int mi = 0; mi < 4; mi++){
        acc[mi][ni] = MFMA(a_h[mi], b_h[ni], acc[mi][ni], 0, 0, 0);
        acc[mi][ni] = MFMA(a_h[mi], b_l[ni], acc[mi][ni], 0, 0, 0);
        if (TERMS == 3)
          acc[mi][ni] = MFMA(a_l[mi], b_h[ni], acc[mi][ni], 0, 0, 0);
      }
    }
  }

  gemm_epilogue<EPI, NB>(p, acc, m0, n0, mo, no, lr, lg);
}

// ---------------------------------------------------------------------------
// gemm2_k (NEW): 256 thr = 4 waves (2x2), tile 128x128, BK=32; ring-2 LDS
// (64KB T3 / 48KB T2 -> 2 blocks/CU), distance-1 prefetch, vmcnt(0)+barrier
// per kt. Each SIMD hosts one wave from each of 2 resident blocks ->
// independent barriers let one block's MFMA phase cover the other's
// LDS read-storm / staging drain. T2 swizzle identical to gemm_k.
// Race safety: per-wave vmcnt(0) precedes s_barrier, so after the barrier
// every wave's gload_lds has landed; the restage-target slot's reads
// retired before the barrier via MFMA data dependence.
// ---------------------------------------------------------------------------
template<int EPI, int TERMS>
__launch_bounds__(256, 2)
__global__ void gemm2_k(GemmP p){
  constexpr int AGR = 512;                       // A granules (128 rows x 4)
  constexpr int NGRAN = (TERMS == 3 ? 2 * AGR : AGR) + 1024;
  constexpr int NG = NGRAN >> 8;                 // glls per wave (4 waves)
  constexpr int NB = 4;
  __shared__ short AhL[2][128 * 32];
  __shared__ short AlL[2][(TERMS == 3) ? 128 * 32 : 8];
  __shared__ short BhL[2][128 * 32];
  __shared__ short BlL[2][128 * 32];
  const int tid = threadIdx.x;
  const int L = tid & 63, w = tid >> 6;          // 4 waves
  const int lr = L & 15, lg = L >> 4;
  const int mo = (w & 1) << 6;
  const int no = (w >> 1) << 6;

  // ---- XCD swizzle: flat%8 = xcd; within xcd, n varies fastest
  const int gx = gridDim.x, gy = gridDim.y;
  const int f = blockIdx.y * gx + blockIdx.x;
  const int j = f >> 3;
  const int jm = j / gx;
  const int mb = (f & 7) * (gy >> 3) + jm;
  const int nb = j - jm * gx;
  const int m0 = mb << 7, n0 = nb << 7;

  const int lrow4 = L >> 2, lq = L & 3;

  int aoff[4], boff[NB];
  #pragma unroll
  for (int mi = 0; mi < 4; mi++){
    int r = mo + (mi << 4) + lr;
    aoff[mi] = (r << 5) + ((lg ^ ((r >> 1) & 3)) << 3);
  }
  #pragma unroll
  for (int ni = 0; ni < NB; ni++){
    int n = no + (ni << 4) + lr;
    boff[ni] = (n << 5) + ((lg ^ ((n >> 1) & 3)) << 3);
  }

  f4v acc[4][NB];
  #pragma unroll
  for (int i = 0; i < 4; i++)
    #pragma unroll
    for (int jj = 0; jj < NB; jj++)
      #pragma unroll
      for (int r = 0; r < 4; r++) acc[i][jj][r] = 0.0f;

  const int nkt = p.K >> 5;

  auto stage = [&](int tile, int slot){
    const int k0 = tile << 5;
    #pragma unroll
    for (int i = 0; i < NG; i++){
      int base_c = (i << 8) + (w << 6);    // wave-uniform granule index
      const short* plane; short* lds; int row0; int ld; int pc;
      if (base_c < AGR){
        pc = base_c; plane = p.Ah; lds = &AhL[slot][0]; row0 = m0; ld = p.lda;
      } else if (TERMS == 3 && base_c < 2 * AGR){
        pc = base_c - AGR; plane = p.Al; lds = &AlL[slot][0]; row0 = m0; ld = p.lda;
      } else {
        int pc2 = base_c - (TERMS == 3 ? 2 * AGR : AGR);
        if (pc2 < 512){ pc = pc2; plane = p.Bh; lds = &BhL[slot][0]; }
        else          { pc = pc2 - 512; plane = p.Bl; lds = &BlL[slot][0]; }
        row0 = n0; ld = p.ldb;
      }
      int rl = (pc >> 2) + lrow4;                 // row within tile
      int sc = (lq ^ ((rl >> 1) & 3)) << 3;       // swizzled source granule
      gload16(plane + (size_t)(row0 + rl) * ld + k0 + sc, lds + (pc << 3));
    }
  };

  // prologue: tile 0 -> slot 0
  stage(0, 0);

  for (int kt = 0; kt < nkt; kt++){
    const int cur = kt & 1;
    // drain own staging, then block-wide sync -> all waves' glls landed
    asm volatile("s_waitcnt vmcnt(0)\n\ts_barrier" ::: "memory");
    // restage the other slot (its reads retired before the barrier)
    if (kt + 1 < nkt) stage(kt + 1, cur ^ 1);

    s8v a_h[4], a_l[4], b_h[NB], b_l[NB];
    #pragma unroll
    for (int mi = 0; mi < 4; mi++){
      a_h[mi] = *(const s8v*)&AhL[cur][aoff[mi]];
      if (TERMS == 3) a_l[mi] = *(const s8v*)&AlL[cur][aoff[mi]];
    }
    #pragma unroll
    for (int ni = 0; ni < NB; ni++){
      b_h[ni] = *(const s8v*)&BhL[cur][boff[ni]];
      b_l[ni] = *(const s8v*)&BlL[cur][boff[ni]];
    }

    #pragma unroll
    for (int ni = 0; ni < NB; ni++){
      #pragma unroll
      for (int mi = 0; mi < 4; mi++){
        acc[mi][ni] = MFMA(a_h[mi], b_h[ni], acc[mi][ni], 0, 0, 0);
        acc[mi][ni] = MFMA(a_h[mi], b_l[ni], acc[mi][ni], 0, 0, 0);
        if (TERMS == 3)
          acc[mi][ni] = MFMA(a_l[mi], b_h[ni], acc[mi][ni], 0, 0, 0);
      }
    }
  }

  gemm_epilogue<EPI, NB>(p, acc, m0, n0, mo, no, lr, lg);
}

// ---------------------------------------------------------------------------
// Flash attention, paired Q-tiles, packed u32 q/K2^T/V^T inputs.
// Per (h,b): Q[1024,64] x K2[64,1024] -> softmax/8 -> x V.
// K packed as K2^T[hb][t][dd], V as V^T[hb][d][s], q as [hb][s][d].
// Block owns Q-tiles (sp, 15-sp) [causal] or (sp, sp+8) [cross].
// ---------------------------------------------------------------------------
template<int CAUSAL>
__launch_bounds__(256, 2)
__global__ void flash_k(const unsigned* __restrict__ qpk,
                        const unsigned* __restrict__ kpk,
                        const unsigned* __restrict__ vpk,
                        short* __restrict__ ohi_g, short* __restrict__ olo_g){
  __shared__ short Kt[2][64*72];       // [t_local][dd] hi/lo
  __shared__ short Vt[2][64*72];       // [d][t_local] hi/lo
  __shared__ unsigned Ps[2][4][16*68]; // per-state, per-wave packed P
  const int tid = threadIdx.x, L = tid & 63, w = tid >> 6;
  const int lr = L & 15, lg = L >> 4;
  const int flat = blockIdx.x + (blockIdx.y << 3);       // grid (8,64)
  const int hb = ((flat & 7) << 3) | ((flat >> 3) & 7);  // same hb -> same XCD
  const int sp = flat >> 6;                              // 0..7
  const int h = hb >> 2, b = hb & 3;
  const size_t hbo = (size_t)hb << 16;
  const float NEG_INF = -__builtin_inff();
  int qt[2]; qt[0] = sp; qt[1] = CAUSAL ? (15 - sp) : (sp + 8);

  s8v qfh[2][2], qfl[2][2];
  #pragma unroll
  for (int st = 0; st < 2; st++){
    const unsigned* qg = qpk + hbo + (size_t)((qt[st] << 6) + (w << 4) + lr) * 64 + (lg << 3);
    #pragma unroll
    for (int ks = 0; ks < 2; ks++){
      u4v p0 = *(const u4v*)(qg + (ks << 5));
      u4v p1 = *(const u4v*)(qg + (ks << 5) + 4);
      #pragma unroll
      for (int jj = 0; jj < 4; jj++){
        qfh[st][ks][jj]     = (short)(p0[jj] & 0xffffu);
        qfl[st][ks][jj]     = (short)(p0[jj] >> 16);
        qfh[st][ks][4 + jj] = (short)(p1[jj] & 0xffffu);
        qfl[st][ks][4 + jj] = (short)(p1[jj] >> 16);
      }
    }
  }

  f4v o[2][4];
  float mprev[2][4], lsum[2][4];
  #pragma unroll
  for (int st = 0; st < 2; st++){
    #pragma unroll
    for (int ni = 0; ni < 4; ni++)
      #pragma unroll
      for (int r = 0; r < 4; r++) o[st][ni][r] = 0.0f;
    #pragma unroll
    for (int r = 0; r < 4; r++){ mprev[st][r] = NEG_INF; lsum[st][r] = 0.0f; }
  }

  const int ntt = CAUSAL ? (qt[1] + 1) : 16;
  for (int ti = 0; ti < ntt; ti++){
    const int t0 = ti << 6;
    const bool actA = !(CAUSAL && ti > qt[0]);
    __syncthreads();
    {
      // stage K tile [tl][dd] and V tile [d][tl]: packed loads, unpack, b128 LDS
      const int row = tid >> 2, col = (tid & 3) << 4;
      const unsigned* kg = kpk + hbo + (size_t)(t0 + row) * 64 + col;
      const unsigned* vg = vpk + hbo + ((size_t)row << 10) + t0 + col;
      unsigned kb[16], vb[16];
      #pragma unroll
      for (int j4 = 0; j4 < 4; j4++){
        *(u4v*)&kb[j4 << 2] = *(const u4v*)(kg + (j4 << 2));
        *(u4v*)&vb[j4 << 2] = *(const u4v*)(vg + (j4 << 2));
      }
      s8v kh0, kh1, kl0, kl1, vh0, vh1, vl0, vl1;
      #pragma unroll
      for (int jj = 0; jj < 8; jj++){
        kh0[jj] = (short)(kb[jj] & 0xffffu);      kl0[jj] = (short)(kb[jj] >> 16);
        kh1[jj] = (short)(kb[8 + jj] & 0xffffu);  kl1[jj] = (short)(kb[8 + jj] >> 16);
        vh0[jj] = (short)(vb[jj] & 0xffffu);      vl0[jj] = (short)(vb[jj] >> 16);
        vh1[jj] = (short)(vb[8 + jj] & 0xffffu);  vl1[jj] = (short)(vb[8 + jj] >> 16);
      }
      const int lb = row * 72 + col;
      *(s8v*)&Kt[0][lb] = kh0;  *(s8v*)&Kt[0][lb + 8] = kh1;
      *(s8v*)&Kt[1][lb] = kl0;  *(s8v*)&Kt[1][lb + 8] = kl1;
      *(s8v*)&Vt[0][lb] = vh0;  *(s8v*)&Vt[0][lb + 8] = vh1;
      *(s8v*)&Vt[1][lb] = vl0;  *(s8v*)&Vt[1][lb + 8] = vl1;
    }
    __syncthreads();

    // ---- QK for both states; K-frags loaded once
    f4v sa[2][4];
    #pragma unroll
    for (int st = 0; st < 2; st++)
      #pragma unroll
      for (int ni = 0; ni < 4; ni++)
        #pragma unroll
        for (int r = 0; r < 4; r++) sa[st][ni][r] = 0.0f;
    #pragma unroll
    for (int ks = 0; ks < 2; ks++){
      const int kb = (ks << 5) + (lg << 3);
      #pragma unroll
      for (int ni = 0; ni < 4; ni++){
        const int tl = (ni << 4) + lr;
        s8v kbh = *(const s8v*)&Kt[0][tl * 72 + kb];
        s8v kbl = *(const s8v*)&Kt[1][tl * 72 + kb];
        if (actA){
          sa[0][ni] = MFMA(qfh[0][ks], kbh, sa[0][ni], 0, 0, 0);
          sa[0][ni] = MFMA(qfh[0][ks], kbl, sa[0][ni], 0, 0, 0);
          sa[0][ni] = MFMA(qfl[0][ks], kbh, sa[0][ni], 0, 0, 0);
        }
        sa[1][ni] = MFMA(qfh[1][ks], kbh, sa[1][ni], 0, 0, 0);
        sa[1][ni] = MFMA(qfh[1][ks], kbl, sa[1][ni], 0, 0, 0);
        sa[1][ni] = MFMA(qfl[1][ks], kbh, sa[1][ni], 0, 0, 0);
      }
    }

    // ---- softmax + P write per state
    #pragma unroll
    for (int st = 0; st < 2; st++){
      if (st == 0 && !actA) continue;
      const int s0w = (qt[st] << 6) + (w << 4);
      const bool diag = CAUSAL && (ti == qt[st]);
      float tm[4] = {NEG_INF, NEG_INF, NEG_INF, NEG_INF};
      #pragma unroll
      for (int ni = 0; ni < 4; ni++)
        #pragma unroll
        for (int r = 0; r < 4; r++){
          float v = sa[st][ni][r] * 0.125f;
          if (diag){
            int tg = t0 + (ni << 4) + lr;
            int sg = s0w + (lg << 2) + r;
            if (tg > sg) v = NEG_INF;
          }
          sa[st][ni][r] = v;
          tm[r] = fmaxf(tm[r], v);
        }
      #pragma unroll
      for (int off = 1; off < 16; off <<= 1)
        #pragma unroll
        for (int r = 0; r < 4; r++) tm[r] = fmaxf(tm[r], __shfl_xor(tm[r], off, 16));
      float alpha[4], psum[4];
      #pragma unroll
      for (int r = 0; r < 4; r++){
        float mn = fmaxf(mprev[st][r], tm[r]);
        alpha[r] = __expf(mprev[st][r] - mn);
        mprev[st][r] = mn;
        psum[r] = 0.0f;
      }
      #pragma unroll
      for (int ni = 0; ni < 4; ni++)
        #pragma unroll
        for (int r = 0; r < 4; r++){
          float pv = __expf(sa[st][ni][r] - mprev[st][r]);
          sa[st][ni][r] = pv;
          psum[r] += pv;
        }
      #pragma unroll
      for (int off = 1; off < 16; off <<= 1)
        #pragma unroll
        for (int r = 0; r < 4; r++) psum[r] += __shfl_xor(psum[r], off, 16);
      #pragma unroll
      for (int r = 0; r < 4; r++) lsum[st][r] = lsum[st][r] * alpha[r] + psum[r];
      #pragma unroll
      for (int ni = 0; ni < 4; ni++)
        #pragma unroll
        for (int r = 0; r < 4; r++) o[st][ni][r] *= alpha[r];
      #pragma unroll
      for (int ni = 0; ni < 4; ni++)
        #pragma unroll
        for (int r = 0; r < 4; r++){
          int prow = (lg << 2) + r, pcol = (ni << 4) + lr;
          Ps[st][w][prow * 68 + pcol] = packf(sa[st][ni][r]);
        }
    }

    // ---- PV for both states; V-frags loaded once (same-wave LDS RAW order)
    #pragma unroll
    for (int ks = 0; ks < 2; ks++){
      const int kb = (ks << 5) + (lg << 3);
      s8v ph[2], pl[2];
      #pragma unroll
      for (int st = 0; st < 2; st++){
        if (st == 0 && !actA) continue;
        u4v p0 = *(const u4v*)&Ps[st][w][lr * 68 + kb];
        u4v p1 = *(const u4v*)&Ps[st][w][lr * 68 + kb + 4];
        #pragma unroll
        for (int jj = 0; jj < 4; jj++){
          ph[st][jj]     = (short)(p0[jj] & 0xffffu);  pl[st][jj]     = (short)(p0[jj] >> 16);
          ph[st][4 + jj] = (short)(p1[jj] & 0xffffu);  pl[st][4 + jj] = (short)(p1[jj] >> 16);
        }
      }
      #pragma unroll
      for (int ni = 0; ni < 4; ni++){
        const int d = (ni << 4) + lr;
        s8v vbh = *(const s8v*)&Vt[0][d * 72 + kb];
        s8v vbl = *(const s8v*)&Vt[1][d * 72 + kb];
        if (actA){
          o[0][ni] = MFMA(ph[0], vbh, o[0][ni], 0, 0, 0);
          o[0][ni] = MFMA(ph[0], vbl, o[0][ni], 0, 0, 0);
          o[0][ni] = MFMA(pl[0], vbh, o[0][ni], 0, 0, 0);
        }
        o[1][ni] = MFMA(ph[1], vbh, o[1][ni], 0, 0, 0);
        o[1][ni] = MFMA(ph[1], vbl, o[1][ni], 0, 0, 0);
        o[1][ni] = MFMA(pl[1], vbh, o[1][ni], 0, 0, 0);
      }
    }
  }

  // ---- normalize, scatter to raw head-concat reshape layout (both states)
  #pragma unroll
  for (int st = 0; st < 2; st++){
    const int s0w = (qt[st] << 6) + (w << 4);
    #pragma unroll
    for (int ni = 0; ni < 4; ni++){
      #pragma unroll
      for (int r = 0; r < 4; r++){
        float val = o[st][ni][r] / lsum[st][r];
        int s = s0w + (lg << 2) + r;
        int d = (ni << 4) + lr;
        int s2i = ((h & 3) << 8) | (b << 6) | (s >> 4);
        int c   = ((s & 15) << 6) | d;
        size_t dst = ((size_t)(h >> 2) << 20) + ((size_t)s2i << 10) + c;
        short hi = f2bf(val);
        ohi_g[dst] = hi;
        olo_g[dst] = f2bf(val - bf2f(hi));
      }
    }
  }
}

// ---------------------------------------------------------------------------
// LayerNorm over (S,E) = 1M elems per batch, three-stage.
// ---------------------------------------------------------------------------
__launch_bounds__(256)
__global__ void ln_partial_k(const float* s1, const float* s2, float2* part){
  const int tid = threadIdx.x, L = tid & 63, w = tid >> 6;
  const int b = blockIdx.y, j = blockIdx.x;
  const size_t base = ((size_t)b << 20) + ((size_t)j << 13) + ((size_t)tid << 2);
  float sum = 0.0f, ss = 0.0f;
  #pragma unroll
  for (int i = 0; i < 8; i++){
    size_t idx = base + ((size_t)i << 10);
    float4 v = *(const float4*)(s1 + idx);
    if (s2){
      float4 u = *(const float4*)(s2 + idx);
      v.x += u.x; v.y += u.y; v.z += u.z; v.w += u.w;
    }
    sum += v.x + v.y + v.z + v.w;
    ss  += v.x*v.x + v.y*v.y + v.z*v.z + v.w*v.w;
  }
  #pragma unroll
  for (int off = 1; off < 64; off <<= 1){
    sum += __shfl_xor(sum, off, 64);
    ss  += __shfl_xor(ss,  off, 64);
  }
  __shared__ float red[4][2];
  if (L == 0){ red[w][0] = sum; red[w][1] = ss; }
  __syncthreads();
  if (tid == 0){
    float s_ = red[0][0] + red[1][0] + red[2][0] + red[3][0];
    float q_ = red[0][1] + red[1][1] + red[2][1] + red[3][1];
    part[b * 128 + j] = make_float2(s_, q_);
  }
}

__launch_bounds__(64)
__global__ void ln_final_k(const float2* part, float2* stats){
  const int b = blockIdx.x, t = threadIdx.x;
  float2 a = part[b * 128 + t], c = part[b * 128 + 64 + t];
  float sum = a.x + c.x, ss = a.y + c.y;
  #pragma unroll
  for (int off = 1; off < 64; off <<= 1){
    sum += __shfl_xor(sum, off, 64);
    ss  += __shfl_xor(ss,  off, 64);
  }
  if (t == 0){
    float mean = sum * (1.0f / 1048576.0f);
    float var  = ss  * (1.0f / 1048576.0f) - mean * mean;
    stats[b] = make_float2(mean, rsqrtf(var + 1e-5f));
  }
}

// MODE 0: hi/lo planes | MODE 1: fp32 + hi/lo planes | MODE 2: fp32 out only
template<int MODE>
__launch_bounds__(256)
__global__ void ln_apply_k(const float* s1, const float* s2,
                           const float* wgt, const float* bias,
                           const float2* stats,
                           float* dstf, short* dsta, short* dstb){
  const int tid = threadIdx.x;
  const size_t base = ((size_t)blockIdx.x << 11) + ((size_t)tid << 2);
  #pragma unroll
  for (int i = 0; i < 2; i++){
    size_t idx = base + ((size_t)i << 10);
    int b = (int)(idx >> 20);
    float2 st = stats[b];
    float4 x = *(const float4*)(s1 + idx);
    if (s2){
      float4 u = *(const float4*)(s2 + idx);
      x.x += u.x; x.y += u.y; x.z += u.z; x.w += u.w;
    }
    unsigned wi = (unsigned)(idx & 1048575u);
    float4 wv = *(const float4*)(wgt + wi);
    float4 bv = *(const float4*)(bias + wi);
    float xv[4] = {x.x, x.y, x.z, x.w};
    float wvv[4] = {wv.x, wv.y, wv.z, wv.w};
    float bvv[4] = {bv.x, bv.y, bv.z, bv.w};
    float yv[4];
    #pragma unroll
    for (int c = 0; c < 4; c++)
      yv[c] = (xv[c] - st.x) * st.y * wvv[c] + bvv[c];
    if (MODE == 0 || MODE == 1){
      short h[4], l[4];
      #pragma unroll
      for (int c = 0; c < 4; c++){
        h[c] = f2bf(yv[c]);
        l[c] = f2bf(yv[c] - bf2f(h[c]));
      }
      *(short4*)(dsta + idx) = make_short4(h[0], h[1], h[2], h[3]);
      *(short4*)(dstb + idx) = make_short4(l[0], l[1], l[2], l[3]);
      if (MODE == 1)
        *(float4*)(dstf + idx) = make_float4(yv[0], yv[1], yv[2], yv[3]);
    } else {
      *(float4*)(dstf + idx) = make_float4(yv[0], yv[1], yv[2], yv[3]);
    }
  }
}

// ---------------------------------------------------------------------------
extern "C" void kernel_launch(void* const* d_in, const int* in_sizes, int n_in,
                              void* d_out, int out_size, void* d_ws, size_t ws_size,
                              hipStream_t stream){
  const float* IRf = (const float*)d_in[0];
  const float* OEf = (const float*)d_in[1];
  const float* Wq1f = (const float*)d_in[2];
  const float* Wk1f = (const float*)d_in[3];
  const float* Wv1f = (const float*)d_in[4];
  const float* Wo1f = (const float*)d_in[5];
  const float* Wq2f = (const float*)d_in[6];
  const float* Wk2f = (const float*)d_in[7];
  const float* Wv2f = (const float*)d_in[8];
  const float* Wo2f = (const float*)d_in[9];
  const float* ln1w = (const float*)d_in[10];
  const float* ln1b = (const float*)d_in[11];
  const float* ln2w = (const float*)d_in[12];
  const float* ln2b = (const float*)d_in[13];
  const float* ln3w = (const float*)d_in[14];
  const float* ln3b = (const float*)d_in[15];
  const float* W1f = (const float*)d_in[16];
  const float* b1f = (const float*)d_in[17];
  const float* W2f = (const float*)d_in[18];
  const float* b2f = (const float*)d_in[19];
  float* dout = (float*)d_out;

  char* ws = (char*)d_ws;
  const size_t MB = (size_t)1 << 20;
  short* OEh = (short*)(ws + 0*MB),  *OEl = (short*)(ws + 8*MB);
  short* IRh = (short*)(ws + 16*MB), *IRl = (short*)(ws + 24*MB);
  short* QKV1t_h = (short*)(ws + 32*MB), *QKV1t_l = (short*)(ws + 38*MB);  // [3072][1024]
  short* Wo1t_h  = (short*)(ws + 44*MB), *Wo1t_l  = (short*)(ws + 46*MB);  // [1024][1024]
  short* Q2t_h   = (short*)(ws + 48*MB), *Q2t_l   = (short*)(ws + 50*MB);
  short* KV2t_h  = (short*)(ws + 52*MB), *KV2t_l  = (short*)(ws + 56*MB);  // [2048][1024]
  short* Wo2t_h  = (short*)(ws + 60*MB), *Wo2t_l  = (short*)(ws + 62*MB);
  short* W1t_h   = (short*)(ws + 64*MB), *W1t_l   = (short*)(ws + 68*MB);  // [2048][1024]
  short* W2t_h   = (short*)(ws + 72*MB), *W2t_l   = (short*)(ws + 76*MB);  // [1024][2048]
  unsigned* q_pk = (unsigned*)(ws + 80*MB);    // packed hi|lo, 16 MB each
  unsigned* k_pk = (unsigned*)(ws + 96*MB);
  unsigned* v_pk = (unsigned*)(ws + 112*MB);
  short* outr_h = (short*)(ws + 128*MB), *outr_l = (short*)(ws + 136*MB);
  float* resid = (float*)(ws + 144*MB);
  short* attn_h = (short*)(ws + 160*MB), *attn_l = (short*)(ws + 168*MB);
  float* att2n_f = (float*)(ws + 176*MB);
  // aliases (dead ranges)
  short* hid_h = (short*)(ws + 80*MB);   // [4096][2048] over q_pk
  short* hid_l = (short*)(ws + 96*MB);   // over k_pk
  float* fc    = (float*)(ws + 112*MB);  // over v_pk
  short* a2n_h = (short*)(ws + 160*MB);  // over attn planes
  short* a2n_l = (short*)(ws + 168*MB);
  float2* part  = (float2*)(ws + 192*MB);
  float2* stats = (float2*)(ws + 192*MB + 65536);

  dim3 blk(256), blkg(512);

  // ---- split OE/IR into bf16 hi/lo planes
  SplitP sp;
  sp.src[0] = OEf; sp.hi[0] = OEh; sp.lo[0] = OEl;
  sp.src[1] = IRf; sp.hi[1] = IRh; sp.lo[1] = IRl;
  splitall_k<<<dim3(4096, 2), blk, 0, stream>>>(sp);

  // ---- batched weight transpose to [N][K] hi/lo planes
  TransP tp;
  const float* tsrc[10] = {Wq1f, Wk1f, Wv1f, Wo1f, Wq2f, Wk2f, Wv2f, Wo2f, W1f, W2f};
  short* toh[10] = {QKV1t_h, QKV1t_h + (1<<20), QKV1t_h + (2<<20), Wo1t_h,
                    Q2t_h, KV2t_h, KV2t_h + (1<<20), Wo2t_h, W1t_h, W2t_h};
  short* tol[10] = {QKV1t_l, QKV1t_l + (1<<20), QKV1t_l + (2<<20), Wo1t_l,
                    Q2t_l, KV2t_l, KV2t_l + (1<<20), Wo2t_l, W1t_l, W2t_l};
  int tK[10]   = {1024,1024,1024,1024,1024,1024,1024,1024,1024,2048};
  int tN[10]   = {1024,1024,1024,1024,1024,1024,1024,1024,2048,1024};
  int tq[10]   = {1,1,1,0,1,1,1,0,0,0};
  int tt[10]   = {256,256,256,256,256,256,256,256,512,512};
  for (int i = 0; i < 10; i++){
    tp.src[i] = tsrc[i]; tp.oh[i] = toh[i]; tp.ol[i] = tol[i];
    tp.Kd[i] = tK[i]; tp.Nd[i] = tN[i]; tp.qkv[i] = tq[i]; tp.ntiles[i] = tt[i];
  }
  transall_k<<<dim3(512, 10), blk, 0, stream>>>(tp);

  GemmP p{};

  // ===== MHA1 (self, causal) =====
  p = {OEh, OEl, 1024, QKV1t_h, QKV1t_l, 1024, 1024, 3072, nullptr, nullptr,
       nullptr, nullptr, nullptr, q_pk, k_pk, v_pk};
  gemm2_k<6,3><<<dim3(24, 32), blk, 0, stream>>>(p);
  flash_k<1><<<dim3(8, 64), blk, 0, stream>>>(q_pk, k_pk, v_pk, outr_h, outr_l);
  p = {outr_h, outr_l, 1024, Wo1t_h, Wo1t_l, 1024, 1024, 1024, OEf, nullptr,
       resid, nullptr, nullptr, nullptr, nullptr, nullptr};
  gemm_k<128,2,3><<<dim3(8, 32), blkg, 0, stream>>>(p);
  ln_partial_k<<<dim3(128, 4), blk, 0, stream>>>(resid, nullptr, part);
  ln_final_k<<<dim3(4), dim3(64), 0, stream>>>(part, stats);
  ln_apply_k<0><<<dim3(2048), blk, 0, stream>>>(resid, nullptr, ln1w, ln1b, stats, nullptr, attn_h, attn_l);

  // ===== MHA2 (cross: KV from inputRes, Q from att_norm, no mask) =====
  p = {attn_h, attn_l, 1024, Q2t_h, Q2t_l, 1024, 1024, 1024, nullptr, nullptr,
       nullptr, nullptr, nullptr, q_pk, nullptr, nullptr};
  gemm_k<128,0,3><<<dim3(8, 32), blkg, 0, stream>>>(p);
  p = {IRh, IRl, 1024, KV2t_h, KV2t_l, 1024, 1024, 2048, nullptr, nullptr,
       nullptr, nullptr, nullptr, k_pk, v_pk, nullptr};
  gemm2_k<7,3><<<dim3(16, 32), blk, 0, stream>>>(p);
  flash_k<0><<<dim3(8, 64), blk, 0, stream>>>(q_pk, k_pk, v_pk, outr_h, outr_l);
  p = {outr_h, outr_l, 1024, Wo2t_h, Wo2t_l, 1024, 1024, 1024, OEf, nullptr,
       resid, nullptr, nullptr, nullptr, nullptr, nullptr};
  gemm_k<128,2,3><<<dim3(8, 32), blkg, 0, stream>>>(p);
  ln_partial_k<<<dim3(128, 4), blk, 0, stream>>>(resid, nullptr, part);
  ln_final_k<<<dim3(4), dim3(64), 0, stream>>>(part, stats);
  ln_apply_k<1><<<dim3(2048), blk, 0, stream>>>(resid, nullptr, ln2w, ln2b, stats, att2n_f, a2n_h, a2n_l);

  // ===== FFN ((B,S,E)->(B,E,S) raw reshape is a flat no-op); 2-term =====
  p = {a2n_h, a2n_l, 1024, W1t_h, W1t_l, 1024, 1024, 2048, nullptr, b1f,
       nullptr, hid_h, hid_l, nullptr, nullptr, nullptr};
  gemm2_k<3,2><<<dim3(16, 32), blk, 0, stream>>>(p);
  p = {hid_h, hid_l, 2048, W2t_h, W2t_l, 2048, 2048, 1024, nullptr, b2f,
       fc, nullptr, nullptr, nullptr, nullptr, nullptr};
  gemm_k<128,4,2><<<dim3(8, 32), blkg, 0, stream>>>(p);
  ln_partial_k<<<dim3(128, 4), blk, 0, stream>>>(fc, att2n_f, part);
  ln_final_k<<<dim3(4), dim3(64), 0, stream>>>(part, stats);
  ln_apply_k<2><<<dim3(2048), blk, 0, stream>>>(fc, att2n_f, ln3w, ln3b, stats, dout, nullptr, nullptr);
}

// Round 7
// 689.433 us; speedup vs baseline: 1.1090x; 1.1090x over previous
//
#include <hip/hip_runtime.h>
#include <cstdint>
#include <cstddef>

// ============================================================================
// transformer_11441792877290 — MI355X fp32, round 13
// B=4 S=1024 E=1024 H=16 DK=64 FF=2048, SCALE=8, EPS=1e-5
// vs round 12 (764us; TM=128 2-block/CU gemm2 lost to scatter write-amp +
// vmcnt(0) drain) and round 10 (690.7us, BEST — restored here verbatim):
//  * All GEMMs back to the r10 gemm_k (ring-3, distance-2, vmcnt(NG),
//    T2 swizzle, 1 block/CU). QKV1 per-active-CU is at the 2-barrier
//    structure's measured ceiling (~955 TF); no further structural edits.
//  * LN stack fused: EPI2 (Wo1/Wo2) and new EPI5 (FFN2: val+bias+att2n)
//    block-reduce sum/sumsq of the LN input they produce and atomicAdd
//    into per-batch accumulators -> ln_partial_k and ln_final_k deleted
//    (6 dispatches, 48MB re-reads). ln_apply_k computes mean/rsqrt from
//    the accumulator. part[] zeroed via hipMemsetAsync (capture-safe).
//  * FFN2 epilogue stores fc+att2n; ln_apply<2> now single-source.
//  Stats summation order changes (~1e-7 rel); all else bit-identical.
// ============================================================================

#define DI __device__ __forceinline__
#define MFMA __builtin_amdgcn_mfma_f32_16x16x32_bf16

typedef short s8v __attribute__((ext_vector_type(8)));
typedef float f4v __attribute__((ext_vector_type(4)));
typedef unsigned u4v __attribute__((ext_vector_type(4)));

DI float bf2f(short u){
  union { unsigned int i; float f; } v;
  v.i = ((unsigned int)(unsigned short)u) << 16;
  return v.f;
}
DI short f2bf(float f){  // round-to-nearest-even
  union { float f; unsigned int i; } v; v.f = f;
  unsigned int x = v.i;
  return (short)((x + 0x7fffu + ((x >> 16) & 1u)) >> 16);
}
DI unsigned pack2(short hi, short lo){
  return ((unsigned)(unsigned short)lo << 16) | (unsigned)(unsigned short)hi;
}
DI unsigned packf(float val){
  short hi = f2bf(val);
  return pack2(hi, f2bf(val - bf2f(hi)));
}
DI void gload16(const void* g, void* l){
  __builtin_amdgcn_global_load_lds(
      (const __attribute__((address_space(1))) unsigned*)g,
      (__attribute__((address_space(3))) unsigned*)l, 16, 0, 0);
}

// ---------------------------------------------------------------------------
// fp32 -> bf16 hi/lo plane split (OE, IR)
// ---------------------------------------------------------------------------
struct SplitP { const float* src[2]; short* hi[2]; short* lo[2]; };

__launch_bounds__(256)
__global__ void splitall_k(SplitP sp){
  const int t = blockIdx.y;
  int i = (blockIdx.x * 256 + threadIdx.x) << 2;
  float4 v = *(const float4*)(sp.src[t] + i);
  float xs[4] = {v.x, v.y, v.z, v.w};
  short h[4], l[4];
  #pragma unroll
  for (int c = 0; c < 4; c++){
    h[c] = f2bf(xs[c]);
    l[c] = f2bf(xs[c] - bf2f(h[c]));
  }
  *(short4*)(sp.hi[t] + i) = make_short4(h[0], h[1], h[2], h[3]);
  *(short4*)(sp.lo[t] + i) = make_short4(l[0], l[1], l[2], l[3]);
}

// ---------------------------------------------------------------------------
// Batched weight transpose: fp32 [K][N] (or [H][E][DK] qkv gather) ->
// bf16 hi/lo planes [N][K]. 64x64 tiles via LDS.
// ---------------------------------------------------------------------------
struct TransP {
  const float* src[10];
  short* oh[10]; short* ol[10];
  int Kd[10]; int Nd[10]; int qkv[10]; int ntiles[10];
};

__launch_bounds__(256)
__global__ void transall_k(TransP tp){
  const int t = blockIdx.y;
  const int tile = blockIdx.x;
  if (tile >= tp.ntiles[t]) return;
  const int K = tp.Kd[t], N = tp.Nd[t];
  const int ncols = N >> 6;
  const int n0 = (tile % ncols) << 6, k0 = (tile / ncols) << 6;
  __shared__ float Ld[64 * 65];
  const int tid = threadIdx.x;
  const int row = tid >> 2, c16 = (tid & 3) << 4;
  const float* s = tp.src[t];
  size_t base;
  if (tp.qkv[t]) base = ((size_t)(n0 >> 6) << 16) + ((size_t)(k0 + row) << 6) + c16;
  else           base = (size_t)(k0 + row) * N + n0 + c16;
  #pragma unroll
  for (int j4 = 0; j4 < 4; j4++){
    float4 v = *(const float4*)(s + base + (j4 << 2));
    int c = row * 65 + c16 + (j4 << 2);
    Ld[c] = v.x; Ld[c + 1] = v.y; Ld[c + 2] = v.z; Ld[c + 3] = v.w;
  }
  __syncthreads();
  const int n = tid >> 2;
  s8v h0, h1, l0, l1;
  #pragma unroll
  for (int j = 0; j < 8; j++){
    float a = Ld[(c16 + j) * 65 + n];
    float b = Ld[(c16 + 8 + j) * 65 + n];
    short ha = f2bf(a), hb = f2bf(b);
    h0[j] = ha; l0[j] = f2bf(a - bf2f(ha));
    h1[j] = hb; l1[j] = f2bf(b - bf2f(hb));
  }
  size_t ob = (size_t)(n0 + n) * K + k0 + c16;
  *(s8v*)(tp.oh[t] + ob)     = h0;
  *(s8v*)(tp.oh[t] + ob + 8) = h1;
  *(s8v*)(tp.ol[t] + ob)     = l0;
  *(s8v*)(tp.ol[t] + ob + 8) = l1;
}

// ---------------------------------------------------------------------------
// Split-bf16 GEMM (r10 structure): C = (Ah+Al)x(Bh+Bl), B given as B^T[N][K].
// 512 thr = 8 waves; tile TM x 128, BK=32; ring-3 LDS, distance-2 prefetch,
// raw s_waitcnt vmcnt(NG)+s_barrier per kt (never vmcnt(0) steady-state),
// single compiler-scheduled region, 1 block/CU.
// T2 XOR swizzle: stage source granule pre-swizzled (linear gload_lds dest)
// + matching swizzled read offsets (granule g ^= (row>>1)&3) -> 0 conflicts.
// TERMS==2 skips the Al plane entirely (NG 6->4 @TM256, 4->3 @TM128).
// EPI 0: packed q scatter              2: fp32 = acc + xres     [+LN stats]
//     3: hi/lo planes = relu(acc+bias) 4: fp32 = acc + bias
//     5: fp32 = acc + bias + xres      [+LN stats]
//     6: QKV packed (q / K2^T / V^T)   7: KV packed (K2^T / V^T)
// ---------------------------------------------------------------------------
struct GemmP {
  const short* Ah; const short* Al; int lda;
  const short* Bh; const short* Bl; int ldb;
  int K; int N;
  const float* xres; const float* bias;
  float* outf;
  short* o1h; short* o1l;
  unsigned* p1; unsigned* p2; unsigned* p3;
  float2* sacc;   // per-batch LN sum/sumsq accumulator (EPI 2/5)
};

template<int TM, int EPI, int TERMS>
__launch_bounds__(512, 2)
__global__ void gemm_k(GemmP p){
  constexpr int AGR = TM * 4;                    // Ah granules (16B) per tile
  constexpr int NGRAN = (TERMS == 3 ? 2 * AGR : AGR) + 1024;  // + Bh + Bl
  constexpr int NG = NGRAN >> 9;                 // gll per wave per tile
  constexpr int WM = TM >> 6;                    // waves along m (4 or 2)
  constexpr int NB = 128 / (8 / WM) / 16;        // n-frags per wave (4 or 2)
  __shared__ short AhL[3][TM * 32];
  __shared__ short AlL[3][(TERMS == 3) ? TM * 32 : 8];
  __shared__ short BhL[3][128 * 32];
  __shared__ short BlL[3][128 * 32];
  const int tid = threadIdx.x;
  const int L = tid & 63, w = tid >> 6;
  const int lr = L & 15, lg = L >> 4;
  const int mo = (w & (WM - 1)) << 6;
  const int no = (w / WM) * (NB << 4);

  // ---- XCD swizzle: flat%8 = xcd; within xcd, n varies fastest
  const int gx = gridDim.x, gy = gridDim.y;
  const int f = blockIdx.y * gx + blockIdx.x;
  const int j = f >> 3;
  const int jm = j / gx;
  const int mb = (f & 7) * (gy >> 3) + jm;
  const int nb = j - jm * gx;
  const int m0 = mb * TM, n0 = nb << 7;

  const int lrow4 = L >> 2, lq = L & 3;

  // ---- swizzled LDS read offsets; row r's k-granule g lives at LDS granule
  // g ^ ((r>>1)&3) -> conflict-free (rocprof-verified 0)
  int aoff[4], boff[NB];
  #pragma unroll
  for (int mi = 0; mi < 4; mi++){
    int r = mo + (mi << 4) + lr;
    aoff[mi] = (r << 5) + ((lg ^ ((r >> 1) & 3)) << 3);
  }
  #pragma unroll
  for (int ni = 0; ni < NB; ni++){
    int n = no + (ni << 4) + lr;
    boff[ni] = (n << 5) + ((lg ^ ((n >> 1) & 3)) << 3);
  }

  f4v acc[4][NB];
  #pragma unroll
  for (int i = 0; i < 4; i++)
    #pragma unroll
    for (int jj = 0; jj < NB; jj++)
      #pragma unroll
      for (int r = 0; r < 4; r++) acc[i][jj][r] = 0.0f;

  const int nkt = p.K >> 5;

  // stage tile into ring slot; source col granule pre-swizzled so the
  // linear gload_lds destination lands swizzled
  auto stage = [&](int tile, int slot){
    const int k0 = tile << 5;
    #pragma unroll
    for (int i = 0; i < NG; i++){
      int base_c = (i << 9) + (w << 6);    // wave-uniform granule index
      const short* plane; short* lds; int row0; int ld; int pc;
      if (base_c < AGR){
        pc = base_c; plane = p.Ah; lds = &AhL[slot][0]; row0 = m0; ld = p.lda;
      } else if (TERMS == 3 && base_c < 2 * AGR){
        pc = base_c - AGR; plane = p.Al; lds = &AlL[slot][0]; row0 = m0; ld = p.lda;
      } else {
        int pc2 = base_c - (TERMS == 3 ? 2 * AGR : AGR);
        if (pc2 < 512){ pc = pc2; plane = p.Bh; lds = &BhL[slot][0]; }
        else          { pc = pc2 - 512; plane = p.Bl; lds = &BlL[slot][0]; }
        row0 = n0; ld = p.ldb;
      }
      int rl = (pc >> 2) + lrow4;                 // row within tile
      int sc = (lq ^ ((rl >> 1) & 3)) << 3;       // swizzled source granule
      gload16(plane + (size_t)(row0 + rl) * ld + k0 + sc, lds + (pc << 3));
    }
  };

  // prologue: tiles 0,1 -> slots 0,1
  stage(0, 0);
  stage(1, 1);

  for (int kt = 0; kt < nkt; kt++){
    const int cur = kt % 3;
    // wait until only the kt+1 prefetch (NG gll) remains in flight, then sync
    asm volatile("s_waitcnt vmcnt(%0)\n\ts_barrier" :: "i"(NG) : "memory");

    s8v a_h[4], a_l[4], b_h[NB], b_l[NB];
    #pragma unroll
    for (int mi = 0; mi < 4; mi++){
      a_h[mi] = *(const s8v*)&AhL[cur][aoff[mi]];
      if (TERMS == 3) a_l[mi] = *(const s8v*)&AlL[cur][aoff[mi]];
    }
    #pragma unroll
    for (int ni = 0; ni < NB; ni++){
      b_h[ni] = *(const s8v*)&BhL[cur][boff[ni]];
      b_l[ni] = *(const s8v*)&BlL[cur][boff[ni]];
    }

    // issue distance-2 prefetch (clamped at the end to keep vmcnt cadence;
    // re-staging the last tile into a dead slot is idempotent/harmless)
    int nt = kt + 2 < nkt ? kt + 2 : nkt - 1;
    stage(nt, (kt + 2) % 3);

    #pragma unroll
    for (int ni = 0; ni < NB; ni++){
      #pragma unroll
      for (int mi = 0; mi < 4; mi++){
        acc[mi][ni] = MFMA(a_h[mi], b_h[ni], acc[mi][ni], 0, 0, 0);
        acc[mi][ni] = MFMA(a_h[mi], b_l[ni], acc[mi][ni], 0, 0, 0);
        if (TERMS == 3)
          acc[mi][ni] = MFMA(a_l[mi], b_h[ni], acc[mi][ni], 0, 0, 0);
      }
    }
  }

  // ---- epilogue (C/D map: col = lane&15, row = (lane>>4)*4 + reg)
  float ls = 0.0f, lss = 0.0f;   // LN stats accumulation (EPI 2/5)
  #pragma unroll
  for (int mi = 0; mi < 4; mi++){
    #pragma unroll
    for (int ni = 0; ni < NB; ni++){
      #pragma unroll
      for (int r = 0; r < 4; r++){
        float val = acc[mi][ni][r];
        int m = m0 + mo + (mi << 4) + (lg << 2) + r;
        int n = n0 + no + (ni << 4) + lr;
        if (EPI == 2){
          size_t o = (size_t)m * p.N + n;
          float x = val + p.xres[o];
          p.outf[o] = x;
          ls += x; lss += x * x;
        } else if (EPI == 5){
          size_t o = (size_t)m * p.N + n;
          float x = val + p.bias[n] + p.xres[o];
          p.outf[o] = x;
          ls += x; lss += x * x;
        } else if (EPI == 4){
          p.outf[(size_t)m * p.N + n] = val + p.bias[n];
        } else if (EPI == 3){
          float x = val + p.bias[n];
          x = x > 0.0f ? x : 0.0f;
          size_t o = (size_t)m * p.N + n;
          short hi = f2bf(x);
          p.o1h[o] = hi;
          p.o1l[o] = f2bf(x - bf2f(hi));
        } else {
          // packed scatter: EPI 0 (q), 6 (q/K2^T/V^T), 7 (K2^T/V^T)
          int seg = (EPI == 0) ? 0 : (n >> 10);
          int n1 = (EPI == 0) ? n : (n & 1023);
          int kind = (EPI == 0) ? 0 : (EPI == 6 ? seg : seg + 1);
          int b = m >> 10, s = m & 1023, hh = n1 >> 6, d = n1 & 63;
          size_t hb16 = (size_t)((hh << 2) | b) << 16;
          size_t dst;
          if (kind == 0)      dst = hb16 + ((size_t)s << 6) + d;
          else if (kind == 1) dst = hb16 + ((size_t)(((s & 15) << 6) | d) << 6) + (s >> 4);
          else                dst = hb16 + ((size_t)d << 10) + s;
          unsigned* dp = (EPI == 0) ? p.p1
                       : (EPI == 6) ? (seg == 0 ? p.p1 : (seg == 1 ? p.p2 : p.p3))
                                    : (seg == 0 ? p.p1 : p.p2);
          dp[dst] = packf(val);
        }
      }
    }
  }

  // ---- fused LN partial stats: block reduce + one atomicAdd per block.
  // EPI 2/5 blocks are TM=128 and lie within one batch (m0>>10 uniform).
  if (EPI == 2 || EPI == 5){
    #pragma unroll
    for (int off = 1; off < 64; off <<= 1){
      ls  += __shfl_xor(ls,  off, 64);
      lss += __shfl_xor(lss, off, 64);
    }
    __shared__ float sred[8][2];
    if (L == 0){ sred[w][0] = ls; sred[w][1] = lss; }
    __syncthreads();
    if (tid == 0){
      float s_ = 0.0f, q_ = 0.0f;
      #pragma unroll
      for (int i = 0; i < 8; i++){ s_ += sred[i][0]; q_ += sred[i][1]; }
      atomicAdd(&p.sacc[m0 >> 10].x, s_);
      atomicAdd(&p.sacc[m0 >> 10].y, q_);
    }
  }
}

// ---------------------------------------------------------------------------
// Flash attention, paired Q-tiles, packed u32 q/K2^T/V^T inputs.
// Per (h,b): Q[1024,64] x K2[64,1024] -> softmax/8 -> x V.
// K packed as K2^T[hb][t][dd], V as V^T[hb][d][s], q as [hb][s][d].
// Block owns Q-tiles (sp, 15-sp) [causal] or (sp, sp+8) [cross].
// ---------------------------------------------------------------------------
template<int CAUSAL>
__launch_bounds__(256, 2)
__global__ void flash_k(const unsigned* __restrict__ qpk,
                        const unsigned* __restrict__ kpk,
                        const unsigned* __restrict__ vpk,
                        short* __restrict__ ohi_g, short* __restrict__ olo_g){
  __shared__ short Kt[2][64*72];       // [t_local][dd] hi/lo
  __shared__ short Vt[2][64*72];       // [d][t_local] hi/lo
  __shared__ unsigned Ps[2][4][16*68]; // per-state, per-wave packed P
  const int tid = threadIdx.x, L = tid & 63, w = tid >> 6;
  const int lr = L & 15, lg = L >> 4;
  const int flat = blockIdx.x + (blockIdx.y << 3);       // grid (8,64)
  const int hb = ((flat & 7) << 3) | ((flat >> 3) & 7);  // same hb -> same XCD
  const int sp = flat >> 6;                              // 0..7
  const int h = hb >> 2, b = hb & 3;
  const size_t hbo = (size_t)hb << 16;
  const float NEG_INF = -__builtin_inff();
  int qt[2]; qt[0] = sp; qt[1] = CAUSAL ? (15 - sp) : (sp + 8);

  s8v qfh[2][2], qfl[2][2];
  #pragma unroll
  for (int st = 0; st < 2; st++){
    const unsigned* qg = qpk + hbo + (size_t)((qt[st] << 6) + (w << 4) + lr) * 64 + (lg << 3);
    #pragma unroll
    for (int ks = 0; ks < 2; ks++){
      u4v p0 = *(const u4v*)(qg + (ks << 5));
      u4v p1 = *(const u4v*)(qg + (ks << 5) + 4);
      #pragma unroll
      for (int jj = 0; jj < 4; jj++){
        qfh[st][ks][jj]     = (short)(p0[jj] & 0xffffu);
        qfl[st][ks][jj]     = (short)(p0[jj] >> 16);
        qfh[st][ks][4 + jj] = (short)(p1[jj] & 0xffffu);
        qfl[st][ks][4 + jj] = (short)(p1[jj] >> 16);
      }
    }
  }

  f4v o[2][4];
  float mprev[2][4], lsum[2][4];
  #pragma unroll
  for (int st = 0; st < 2; st++){
    #pragma unroll
    for (int ni = 0; ni < 4; ni++)
      #pragma unroll
      for (int r = 0; r < 4; r++) o[st][ni][r] = 0.0f;
    #pragma unroll
    for (int r = 0; r < 4; r++){ mprev[st][r] = NEG_INF; lsum[st][r] = 0.0f; }
  }

  const int ntt = CAUSAL ? (qt[1] + 1) : 16;
  for (int ti = 0; ti < ntt; ti++){
    const int t0 = ti << 6;
    const bool actA = !(CAUSAL && ti > qt[0]);
    __syncthreads();
    {
      // stage K tile [tl][dd] and V tile [d][tl]: packed loads, unpack, b128 LDS
      const int row = tid >> 2, col = (tid & 3) << 4;
      const unsigned* kg = kpk + hbo + (size_t)(t0 + row) * 64 + col;
      const unsigned* vg = vpk + hbo + ((size_t)row << 10) + t0 + col;
      unsigned kb[16], vb[16];
      #pragma unroll
      for (int j4 = 0; j4 < 4; j4++){
        *(u4v*)&kb[j4 << 2] = *(const u4v*)(kg + (j4 << 2));
        *(u4v*)&vb[j4 << 2] = *(const u4v*)(vg + (j4 << 2));
      }
      s8v kh0, kh1, kl0, kl1, vh0, vh1, vl0, vl1;
      #pragma unroll
      for (int jj = 0; jj < 8; jj++){
        kh0[jj] = (short)(kb[jj] & 0xffffu);      kl0[jj] = (short)(kb[jj] >> 16);
        kh1[jj] = (short)(kb[8 + jj] & 0xffffu);  kl1[jj] = (short)(kb[8 + jj] >> 16);
        vh0[jj] = (short)(vb[jj] & 0xffffu);      vl0[jj] = (short)(vb[jj] >> 16);
        vh1[jj] = (short)(vb[8 + jj] & 0xffffu);  vl1[jj] = (short)(vb[8 + jj] >> 16);
      }
      const int lb = row * 72 + col;
      *(s8v*)&Kt[0][lb] = kh0;  *(s8v*)&Kt[0][lb + 8] = kh1;
      *(s8v*)&Kt[1][lb] = kl0;  *(s8v*)&Kt[1][lb + 8] = kl1;
      *(s8v*)&Vt[0][lb] = vh0;  *(s8v*)&Vt[0][lb + 8] = vh1;
      *(s8v*)&Vt[1][lb] = vl0;  *(s8v*)&Vt[1][lb + 8] = vl1;
    }
    __syncthreads();

    // ---- QK for both states; K-frags loaded once
    f4v sa[2][4];
    #pragma unroll
    for (int st = 0; st < 2; st++)
      #pragma unroll
      for (int ni = 0; ni < 4; ni++)
        #pragma unroll
        for (int r = 0; r < 4; r++) sa[st][ni][r] = 0.0f;
    #pragma unroll
    for (int ks = 0; ks < 2; ks++){
      const int kb = (ks << 5) + (lg << 3);
      #pragma unroll
      for (int ni = 0; ni < 4; ni++){
        const int tl = (ni << 4) + lr;
        s8v kbh = *(const s8v*)&Kt[0][tl * 72 + kb];
        s8v kbl = *(const s8v*)&Kt[1][tl * 72 + kb];
        if (actA){
          sa[0][ni] = MFMA(qfh[0][ks], kbh, sa[0][ni], 0, 0, 0);
          sa[0][ni] = MFMA(qfh[0][ks], kbl, sa[0][ni], 0, 0, 0);
          sa[0][ni] = MFMA(qfl[0][ks], kbh, sa[0][ni], 0, 0, 0);
        }
        sa[1][ni] = MFMA(qfh[1][ks], kbh, sa[1][ni], 0, 0, 0);
        sa[1][ni] = MFMA(qfh[1][ks], kbl, sa[1][ni], 0, 0, 0);
        sa[1][ni] = MFMA(qfl[1][ks], kbh, sa[1][ni], 0, 0, 0);
      }
    }

    // ---- softmax + P write per state
    #pragma unroll
    for (int st = 0; st < 2; st++){
      if (st == 0 && !actA) continue;
      const int s0w = (qt[st] << 6) + (w << 4);
      const bool diag = CAUSAL && (ti == qt[st]);
      float tm[4] = {NEG_INF, NEG_INF, NEG_INF, NEG_INF};
      #pragma unroll
      for (int ni = 0; ni < 4; ni++)
        #pragma unroll
        for (int r = 0; r < 4; r++){
          float v = sa[st][ni][r] * 0.125f;
          if (diag){
            int tg = t0 + (ni << 4) + lr;
            int sg = s0w + (lg << 2) + r;
            if (tg > sg) v = NEG_INF;
          }
          sa[st][ni][r] = v;
          tm[r] = fmaxf(tm[r], v);
        }
      #pragma unroll
      for (int off = 1; off < 16; off <<= 1)
        #pragma unroll
        for (int r = 0; r < 4; r++) tm[r] = fmaxf(tm[r], __shfl_xor(tm[r], off, 16));
      float alpha[4], psum[4];
      #pragma unroll
      for (int r = 0; r < 4; r++){
        float mn = fmaxf(mprev[st][r], tm[r]);
        alpha[r] = __expf(mprev[st][r] - mn);
        mprev[st][r] = mn;
        psum[r] = 0.0f;
      }
      #pragma unroll
      for (int ni = 0; ni < 4; ni++)
        #pragma unroll
        for (int r = 0; r < 4; r++){
          float pv = __expf(sa[st][ni][r] - mprev[st][r]);
          sa[st][ni][r] = pv;
          psum[r] += pv;
        }
      #pragma unroll
      for (int off = 1; off < 16; off <<= 1)
        #pragma unroll
        for (int r = 0; r < 4; r++) psum[r] += __shfl_xor(psum[r], off, 16);
      #pragma unroll
      for (int r = 0; r < 4; r++) lsum[st][r] = lsum[st][r] * alpha[r] + psum[r];
      #pragma unroll
      for (int ni = 0; ni < 4; ni++)
        #pragma unroll
        for (int r = 0; r < 4; r++) o[st][ni][r] *= alpha[r];
      #pragma unroll
      for (int ni = 0; ni < 4; ni++)
        #pragma unroll
        for (int r = 0; r < 4; r++){
          int prow = (lg << 2) + r, pcol = (ni << 4) + lr;
          Ps[st][w][prow * 68 + pcol] = packf(sa[st][ni][r]);
        }
    }

    // ---- PV for both states; V-frags loaded once (same-wave LDS RAW order)
    #pragma unroll
    for (int ks = 0; ks < 2; ks++){
      const int kb = (ks << 5) + (lg << 3);
      s8v ph[2], pl[2];
      #pragma unroll
      for (int st = 0; st < 2; st++){
        if (st == 0 && !actA) continue;
        u4v p0 = *(const u4v*)&Ps[st][w][lr * 68 + kb];
        u4v p1 = *(const u4v*)&Ps[st][w][lr * 68 + kb + 4];
        #pragma unroll
        for (int jj = 0; jj < 4; jj++){
          ph[st][jj]     = (short)(p0[jj] & 0xffffu);  pl[st][jj]     = (short)(p0[jj] >> 16);
          ph[st][4 + jj] = (short)(p1[jj] & 0xffffu);  pl[st][4 + jj] = (short)(p1[jj] >> 16);
        }
      }
      #pragma unroll
      for (int ni = 0; ni < 4; ni++){
        const int d = (ni << 4) + lr;
        s8v vbh = *(const s8v*)&Vt[0][d * 72 + kb];
        s8v vbl = *(const s8v*)&Vt[1][d * 72 + kb];
        if (actA){
          o[0][ni] = MFMA(ph[0], vbh, o[0][ni], 0, 0, 0);
          o[0][ni] = MFMA(ph[0], vbl, o[0][ni], 0, 0, 0);
          o[0][ni] = MFMA(pl[0], vbh, o[0][ni], 0, 0, 0);
        }
        o[1][ni] = MFMA(ph[1], vbh, o[1][ni], 0, 0, 0);
        o[1][ni] = MFMA(ph[1], vbl, o[1][ni], 0, 0, 0);
        o[1][ni] = MFMA(pl[1], vbh, o[1][ni], 0, 0, 0);
      }
    }
  }

  // ---- normalize, scatter to raw head-concat reshape layout (both states)
  #pragma unroll
  for (int st = 0; st < 2; st++){
    const int s0w = (qt[st] << 6) + (w << 4);
    #pragma unroll
    for (int ni = 0; ni < 4; ni++){
      #pragma unroll
      for (int r = 0; r < 4; r++){
        float val = o[st][ni][r] / lsum[st][r];
        int s = s0w + (lg << 2) + r;
        int d = (ni << 4) + lr;
        int s2i = ((h & 3) << 8) | (b << 6) | (s >> 4);
        int c   = ((s & 15) << 6) | d;
        size_t dst = ((size_t)(h >> 2) << 20) + ((size_t)s2i << 10) + c;
        short hi = f2bf(val);
        ohi_g[dst] = hi;
        olo_g[dst] = f2bf(val - bf2f(hi));
      }
    }
  }
}

// ---------------------------------------------------------------------------
// LayerNorm apply: stats read from fused per-batch accumulators (sum, sumsq
// over 1M elems) produced by the GEMM epilogues (EPI 2/5).
// MODE 0: hi/lo planes | MODE 1: fp32 + hi/lo planes | MODE 2: fp32 out only
// ---------------------------------------------------------------------------
template<int MODE>
__launch_bounds__(256)
__global__ void ln_apply_k(const float* s1, const float* s2,
                           const float* wgt, const float* bias,
                           const float2* sacc,
                           float* dstf, short* dsta, short* dstb){
  const int tid = threadIdx.x;
  const size_t base = ((size_t)blockIdx.x << 11) + ((size_t)tid << 2);
  #pragma unroll
  for (int i = 0; i < 2; i++){
    size_t idx = base + ((size_t)i << 10);
    int b = (int)(idx >> 20);
    float2 sp = sacc[b];
    float mean = sp.x * (1.0f / 1048576.0f);
    float rstd = rsqrtf(sp.y * (1.0f / 1048576.0f) - mean * mean + 1e-5f);
    float4 x = *(const float4*)(s1 + idx);
    if (s2){
      float4 u = *(const float4*)(s2 + idx);
      x.x += u.x; x.y += u.y; x.z += u.z; x.w += u.w;
    }
    unsigned wi = (unsigned)(idx & 1048575u);
    float4 wv = *(const float4*)(wgt + wi);
    float4 bv = *(const float4*)(bias + wi);
    float xv[4] = {x.x, x.y, x.z, x.w};
    float wvv[4] = {wv.x, wv.y, wv.z, wv.w};
    float bvv[4] = {bv.x, bv.y, bv.z, bv.w};
    float yv[4];
    #pragma unroll
    for (int c = 0; c < 4; c++)
      yv[c] = (xv[c] - mean) * rstd * wvv[c] + bvv[c];
    if (MODE == 0 || MODE == 1){
      short h[4], l[4];
      #pragma unroll
      for (int c = 0; c < 4; c++){
        h[c] = f2bf(yv[c]);
        l[c] = f2bf(yv[c] - bf2f(h[c]));
      }
      *(short4*)(dsta + idx) = make_short4(h[0], h[1], h[2], h[3]);
      *(short4*)(dstb + idx) = make_short4(l[0], l[1], l[2], l[3]);
      if (MODE == 1)
        *(float4*)(dstf + idx) = make_float4(yv[0], yv[1], yv[2], yv[3]);
    } else {
      *(float4*)(dstf + idx) = make_float4(yv[0], yv[1], yv[2], yv[3]);
    }
  }
}

// ---------------------------------------------------------------------------
extern "C" void kernel_launch(void* const* d_in, const int* in_sizes, int n_in,
                              void* d_out, int out_size, void* d_ws, size_t ws_size,
                              hipStream_t stream){
  const float* IRf = (const float*)d_in[0];
  const float* OEf = (const float*)d_in[1];
  const float* Wq1f = (const float*)d_in[2];
  const float* Wk1f = (const float*)d_in[3];
  const float* Wv1f = (const float*)d_in[4];
  const float* Wo1f = (const float*)d_in[5];
  const float* Wq2f = (const float*)d_in[6];
  const float* Wk2f = (const float*)d_in[7];
  const float* Wv2f = (const float*)d_in[8];
  const float* Wo2f = (const float*)d_in[9];
  const float* ln1w = (const float*)d_in[10];
  const float* ln1b = (const float*)d_in[11];
  const float* ln2w = (const float*)d_in[12];
  const float* ln2b = (const float*)d_in[13];
  const float* ln3w = (const float*)d_in[14];
  const float* ln3b = (const float*)d_in[15];
  const float* W1f = (const float*)d_in[16];
  const float* b1f = (const float*)d_in[17];
  const float* W2f = (const float*)d_in[18];
  const float* b2f = (const float*)d_in[19];
  float* dout = (float*)d_out;

  char* ws = (char*)d_ws;
  const size_t MB = (size_t)1 << 20;
  short* OEh = (short*)(ws + 0*MB),  *OEl = (short*)(ws + 8*MB);
  short* IRh = (short*)(ws + 16*MB), *IRl = (short*)(ws + 24*MB);
  short* QKV1t_h = (short*)(ws + 32*MB), *QKV1t_l = (short*)(ws + 38*MB);  // [3072][1024]
  short* Wo1t_h  = (short*)(ws + 44*MB), *Wo1t_l  = (short*)(ws + 46*MB);  // [1024][1024]
  short* Q2t_h   = (short*)(ws + 48*MB), *Q2t_l   = (short*)(ws + 50*MB);
  short* KV2t_h  = (short*)(ws + 52*MB), *KV2t_l  = (short*)(ws + 56*MB);  // [2048][1024]
  short* Wo2t_h  = (short*)(ws + 60*MB), *Wo2t_l  = (short*)(ws + 62*MB);
  short* W1t_h   = (short*)(ws + 64*MB), *W1t_l   = (short*)(ws + 68*MB);  // [2048][1024]
  short* W2t_h   = (short*)(ws + 72*MB), *W2t_l   = (short*)(ws + 76*MB);  // [1024][2048]
  unsigned* q_pk = (unsigned*)(ws + 80*MB);    // packed hi|lo, 16 MB each
  unsigned* k_pk = (unsigned*)(ws + 96*MB);
  unsigned* v_pk = (unsigned*)(ws + 112*MB);
  short* outr_h = (short*)(ws + 128*MB), *outr_l = (short*)(ws + 136*MB);
  float* resid = (float*)(ws + 144*MB);
  short* attn_h = (short*)(ws + 160*MB), *attn_l = (short*)(ws + 168*MB);
  float* att2n_f = (float*)(ws + 176*MB);
  // aliases (dead ranges)
  short* hid_h = (short*)(ws + 80*MB);   // [4096][2048] over q_pk
  short* hid_l = (short*)(ws + 96*MB);   // over k_pk
  float* fc    = (float*)(ws + 112*MB);  // over v_pk
  short* a2n_h = (short*)(ws + 160*MB);  // over attn planes
  short* a2n_l = (short*)(ws + 168*MB);
  float2* part  = (float2*)(ws + 192*MB);  // 12 float2: LN1[0..3] LN2[4..7] LN3[8..11]

  dim3 blk(256), blkg(512);

  // ---- zero LN accumulators (captured per graph replay)
  hipMemsetAsync(part, 0, 12 * sizeof(float2), stream);

  // ---- split OE/IR into bf16 hi/lo planes
  SplitP sp;
  sp.src[0] = OEf; sp.hi[0] = OEh; sp.lo[0] = OEl;
  sp.src[1] = IRf; sp.hi[1] = IRh; sp.lo[1] = IRl;
  splitall_k<<<dim3(4096, 2), blk, 0, stream>>>(sp);

  // ---- batched weight transpose to [N][K] hi/lo planes
  TransP tp;
  const float* tsrc[10] = {Wq1f, Wk1f, Wv1f, Wo1f, Wq2f, Wk2f, Wv2f, Wo2f, W1f, W2f};
  short* toh[10] = {QKV1t_h, QKV1t_h + (1<<20), QKV1t_h + (2<<20), Wo1t_h,
                    Q2t_h, KV2t_h, KV2t_h + (1<<20), Wo2t_h, W1t_h, W2t_h};
  short* tol[10] = {QKV1t_l, QKV1t_l + (1<<20), QKV1t_l + (2<<20), Wo1t_l,
                    Q2t_l, KV2t_l, KV2t_l + (1<<20), Wo2t_l, W1t_l, W2t_l};
  int tK[10]   = {1024,1024,1024,1024,1024,1024,1024,1024,1024,2048};
  int tN[10]   = {1024,1024,1024,1024,1024,1024,1024,1024,2048,1024};
  int tq[10]   = {1,1,1,0,1,1,1,0,0,0};
  int tt[10]   = {256,256,256,256,256,256,256,256,512,512};
  for (int i = 0; i < 10; i++){
    tp.src[i] = tsrc[i]; tp.oh[i] = toh[i]; tp.ol[i] = tol[i];
    tp.Kd[i] = tK[i]; tp.Nd[i] = tN[i]; tp.qkv[i] = tq[i]; tp.ntiles[i] = tt[i];
  }
  transall_k<<<dim3(512, 10), blk, 0, stream>>>(tp);

  GemmP p{};

  // ===== MHA1 (self, causal) =====
  p = {OEh, OEl, 1024, QKV1t_h, QKV1t_l, 1024, 1024, 3072, nullptr, nullptr,
       nullptr, nullptr, nullptr, q_pk, k_pk, v_pk, nullptr};
  gemm_k<256,6,3><<<dim3(24, 16), blkg, 0, stream>>>(p);
  flash_k<1><<<dim3(8, 64), blk, 0, stream>>>(q_pk, k_pk, v_pk, outr_h, outr_l);
  p = {outr_h, outr_l, 1024, Wo1t_h, Wo1t_l, 1024, 1024, 1024, OEf, nullptr,
       resid, nullptr, nullptr, nullptr, nullptr, nullptr, part};
  gemm_k<128,2,3><<<dim3(8, 32), blkg, 0, stream>>>(p);
  ln_apply_k<0><<<dim3(2048), blk, 0, stream>>>(resid, nullptr, ln1w, ln1b, part, nullptr, attn_h, attn_l);

  // ===== MHA2 (cross: KV from inputRes, Q from att_norm, no mask) =====
  p = {attn_h, attn_l, 1024, Q2t_h, Q2t_l, 1024, 1024, 1024, nullptr, nullptr,
       nullptr, nullptr, nullptr, q_pk, nullptr, nullptr, nullptr};
  gemm_k<128,0,3><<<dim3(8, 32), blkg, 0, stream>>>(p);
  p = {IRh, IRl, 1024, KV2t_h, KV2t_l, 1024, 1024, 2048, nullptr, nullptr,
       nullptr, nullptr, nullptr, k_pk, v_pk, nullptr, nullptr};
  gemm_k<256,7,3><<<dim3(16, 16), blkg, 0, stream>>>(p);
  flash_k<0><<<dim3(8, 64), blk, 0, stream>>>(q_pk, k_pk, v_pk, outr_h, outr_l);
  p = {outr_h, outr_l, 1024, Wo2t_h, Wo2t_l, 1024, 1024, 1024, OEf, nullptr,
       resid, nullptr, nullptr, nullptr, nullptr, nullptr, part + 4};
  gemm_k<128,2,3><<<dim3(8, 32), blkg, 0, stream>>>(p);
  ln_apply_k<1><<<dim3(2048), blk, 0, stream>>>(resid, nullptr, ln2w, ln2b, part + 4, att2n_f, a2n_h, a2n_l);

  // ===== FFN ((B,S,E)->(B,E,S) raw reshape is a flat no-op); 2-term =====
  p = {a2n_h, a2n_l, 1024, W1t_h, W1t_l, 1024, 1024, 2048, nullptr, b1f,
       nullptr, hid_h, hid_l, nullptr, nullptr, nullptr, nullptr};
  gemm_k<256,3,2><<<dim3(16, 16), blkg, 0, stream>>>(p);
  // FFN2 epilogue stores fc+att2n and accumulates LN3 stats (EPI 5)
  p = {hid_h, hid_l, 2048, W2t_h, W2t_l, 2048, 2048, 1024, att2n_f, b2f,
       fc, nullptr, nullptr, nullptr, nullptr, nullptr, part + 8};
  gemm_k<128,5,2><<<dim3(8, 32), blkg, 0, stream>>>(p);
  ln_apply_k<2><<<dim3(2048), blk, 0, stream>>>(fc, nullptr, ln3w, ln3b, part + 8, dout, nullptr, nullptr);
}